// Round 2
// baseline (491.534 us; speedup 1.0000x reference)
//
#include <hip/hip_runtime.h>

// BacklashNet: per-row nonlinear scan, parallelized by speculative chunking.
//
// Step (bit-exact vs JAX/numpy fp32 reference, no FMA contraction):
//   lo=fl(fl(m_lo*x)+fl(m_lo*c_lo)); up analog; f1=(lo<=prev); f2=(fl(prev-A2)<=muc)
//   out = f1 ? (f2 ? fl(fl(lo+A2)+muc) : lo) : (f2 ? up : prev)
// The map prev->out is {const, identity-band, const}; with x~N(0,1) the identity
// band cannot be occupied for ~64 consecutive steps, so 64-step chunk maps are
// (almost always) entry-independent constants. We speculate chunk entries and
// validate by BITWISE equality of the speculated entry vs the true running state;
// mismatches fall back to inline sequential recompute (sound unconditionally).
// (+-0 entry aliasing is benign: bstep produces identical bits from -0/+0 except
// the identity passthrough itself, which stays a +-0 difference => absmax 0.)
//
// Workspace: 3 * B*NC floats = 3 MB of d_ws (exit0, exit1, true-entries).

namespace {

constexpr int kB     = 2048;
constexpr int kT     = 8192;
constexpr int kL     = 64;        // chunk length (timesteps)
constexpr int kNC    = kT / kL;   // 128 chunks per row
constexpr int kLogNC = 7;

__device__ __forceinline__ float bstep(float xv, float prev, float m_lo, float m_up,
                                       float mlc, float muc) {
  float A1 = __fmul_rn(m_lo, xv);
  float B1 = __fadd_rn(A1, mlc);                  // "lo"
  float A2 = __fmul_rn(m_up, xv);
  float B2 = __fadd_rn(A2, muc);                  // "up"
  float C  = __fadd_rn(__fadd_rn(B1, A2), muc);   // f1&f2 case, exact ref ordering
  float u  = __fsub_rn(prev, A2);
  bool  f1 = (B1 <= prev);                        // sign-exact: s1 <= 0
  bool  f2 = (u <= muc);                          // sign-exact: s2 <= 0
  float hi = f2 ? C  : B1;
  float lo = f2 ? B2 : prev;
  return f1 ? hi : lo;
}

// Run one 64-step chunk from state p. xv points at the chunk's 16 float4s.
template <bool WRITE>
__device__ __forceinline__ float run_chunk(const float4* __restrict__ xv,
                                           float4* __restrict__ ov, float p,
                                           float m_lo, float m_up, float mlc, float muc) {
#pragma unroll
  for (int i = 0; i < kL / 4; ++i) {
    float4 a = xv[i];
    float4 o;
    p = bstep(a.x, p, m_lo, m_up, mlc, muc); o.x = p;
    p = bstep(a.y, p, m_lo, m_up, mlc, muc); o.y = p;
    p = bstep(a.z, p, m_lo, m_up, mlc, muc); o.z = p;
    p = bstep(a.w, p, m_lo, m_up, mlc, muc); o.w = p;
    if (WRITE) ov[i] = o;
  }
  return p;
}

// Pass A0: run every chunk from a guess (true p0 for c==0, 0.0 otherwise).
__global__ __launch_bounds__(256) void pass_a0(
    const float* __restrict__ x, const float* __restrict__ p0,
    const float* __restrict__ w, float* __restrict__ exit0) {
  const int tid = blockIdx.x * 256 + threadIdx.x;
  const int r = tid >> kLogNC, c = tid & (kNC - 1);
  const float m_lo = w[0], m_up = w[1];
  const float mlc = __fmul_rn(m_lo, w[2]), muc = __fmul_rn(m_up, w[3]);
  const float entry = (c == 0) ? p0[r] : 0.0f;
  const float4* xv = reinterpret_cast<const float4*>(x + (size_t)r * kT + c * kL);
  exit0[r * kNC + c] =
      run_chunk<false>(xv, nullptr, entry, m_lo, m_up, mlc, muc);
}

// Pass A1: rerun every chunk from entry = exit0 of the previous chunk.
__global__ __launch_bounds__(256) void pass_a1(
    const float* __restrict__ x, const float* __restrict__ p0,
    const float* __restrict__ w, const float* __restrict__ exit0,
    float* __restrict__ exit1) {
  const int tid = blockIdx.x * 256 + threadIdx.x;
  const int r = tid >> kLogNC, c = tid & (kNC - 1);
  const float m_lo = w[0], m_up = w[1];
  const float mlc = __fmul_rn(m_lo, w[2]), muc = __fmul_rn(m_up, w[3]);
  const float entry = (c == 0) ? p0[r] : exit0[r * kNC + c - 1];
  const float4* xv = reinterpret_cast<const float4*>(x + (size_t)r * kT + c * kL);
  exit1[r * kNC + c] =
      run_chunk<false>(xv, nullptr, entry, m_lo, m_up, mlc, muc);
}

// Pass B: per-row serial walk over chunks; validate speculation bitwise,
// fall back to inline recompute on mismatch. Writes true chunk entries.
__global__ __launch_bounds__(64) void pass_b(
    const float* __restrict__ x, const float* __restrict__ p0,
    const float* __restrict__ w, const float* __restrict__ exit0,
    const float* __restrict__ exit1, float* __restrict__ ent) {
  const int r = blockIdx.x * 64 + threadIdx.x;
  const float m_lo = w[0], m_up = w[1];
  const float mlc = __fmul_rn(m_lo, w[2]), muc = __fmul_rn(m_up, w[3]);
  float t = p0[r];
#pragma unroll 1
  for (int c = 0; c < kNC; ++c) {
    ent[c * kB + r] = t;  // true entry of chunk c (coalesced across lanes)
    const float used = (c == 0) ? p0[r] : exit0[r * kNC + c - 1];
    const float ex   = exit1[r * kNC + c];
    if (used == t) {
      t = ex;  // speculation validated: A1 ran this chunk from exactly t
    } else {
      const float4* xv = reinterpret_cast<const float4*>(x + (size_t)r * kT + c * kL);
      t = run_chunk<false>(xv, nullptr, t, m_lo, m_up, mlc, muc);
    }
  }
}

// Pass C: recompute all chunk interiors from true entries, write outputs.
__global__ __launch_bounds__(256) void pass_c(
    const float* __restrict__ x, const float* __restrict__ w,
    const float* __restrict__ ent, float* __restrict__ out) {
  const int tid = blockIdx.x * 256 + threadIdx.x;
  const int r = tid >> kLogNC, c = tid & (kNC - 1);
  const float m_lo = w[0], m_up = w[1];
  const float mlc = __fmul_rn(m_lo, w[2]), muc = __fmul_rn(m_up, w[3]);
  const float entry = ent[c * kB + r];
  const float4* xv = reinterpret_cast<const float4*>(x + (size_t)r * kT + c * kL);
  float4* ov = reinterpret_cast<float4*>(out + (size_t)r * kT + c * kL);
  run_chunk<true>(xv, ov, entry, m_lo, m_up, mlc, muc);
}

}  // namespace

extern "C" void kernel_launch(void* const* d_in, const int* in_sizes, int n_in,
                              void* d_out, int out_size, void* d_ws, size_t ws_size,
                              hipStream_t stream) {
  const float* x  = (const float*)d_in[0];   // (B, T, 1) fp32
  const float* p0 = (const float*)d_in[1];   // (B, 1, 1) fp32
  const float* w  = (const float*)d_in[2];   // (4,) fp32
  float* out = (float*)d_out;                // (B, T, 1) fp32
  (void)in_sizes; (void)n_in; (void)out_size; (void)ws_size;

  float* exit0 = (float*)d_ws;               // B*NC floats
  float* exit1 = exit0 + (size_t)kB * kNC;   // B*NC floats
  float* ent   = exit1 + (size_t)kB * kNC;   // B*NC floats  (3 MB total)

  const int nchunk_threads = kB * kNC;       // 262144
  pass_a0<<<nchunk_threads / 256, 256, 0, stream>>>(x, p0, w, exit0);
  pass_a1<<<nchunk_threads / 256, 256, 0, stream>>>(x, p0, w, exit0, exit1);
  pass_b <<<kB / 64, 64, 0, stream>>>(x, p0, w, exit0, exit1, ent);
  pass_c <<<nchunk_threads / 256, 256, 0, stream>>>(x, w, ent, out);
}